// Round 1
// baseline (2257.375 us; speedup 1.0000x reference)
//
#include <hip/hip_runtime.h>

// BlindSpotConv == Conv2d(64->64, k=3, pad=1) + bias, fp32 NCHW 16x64x256x256.
//
// Strategy (round 1): direct conv, fp32 vector ALU (no fp32 MFMA on CDNA4).
//  - 32x8 output pixels per block, 1 pixel/thread, 64 oc accumulators in VGPRs.
//  - Input staged in LDS, 32-ic chunks (34x10 halo tile per ic, 43.5 KB).
//  - Weights repacked to [ic][kh][kw][oc] in d_ws so inner-oc reads are
//    wave-uniform + contiguous -> scalar loads (s_load_dwordx16), freeing VALU.

#define N_   16
#define IC_  64
#define OC_  64
#define HW_  256
#define ICB  32           // input-channel chunk staged in LDS
#define TH   8            // output tile height per block
#define TW   32           // output tile width per block

__global__ void repack_w(const float* __restrict__ W, float* __restrict__ Wt) {
    int i = blockIdx.x * 256 + threadIdx.x;
    if (i < IC_ * 3 * 3 * OC_) {
        int oc = i & (OC_ - 1);
        int t  = i >> 6;          // (ic*3+kh)*3+kw
        int kw = t % 3; t /= 3;
        int kh = t % 3;
        int ic = t / 3;
        Wt[i] = W[((oc * IC_ + ic) * 3 + kh) * 3 + kw];
    }
}

template <bool REPACKED>
__global__ __launch_bounds__(256) void conv3x3(const float* __restrict__ x,
                                               const float* __restrict__ Wt,
                                               const float* __restrict__ bias,
                                               float* __restrict__ out) {
    __shared__ float sx[ICB][TH + 2][TW + 2];   // 32*10*34*4 = 43520 B

    const int tx  = threadIdx.x;                 // 0..31 -> w
    const int ty  = threadIdx.y;                 // 0..7  -> h
    const int tid = ty * TW + tx;
    const int w0  = blockIdx.x * TW;
    const int h0  = blockIdx.y * TH;
    const int n   = blockIdx.z;

    float acc[OC_];
    #pragma unroll
    for (int oc = 0; oc < OC_; ++oc) acc[oc] = bias[oc];   // uniform s_loads

    const int h = h0 + ty;
    const int w = w0 + tx;

    for (int icc = 0; icc < IC_; icc += ICB) {
        // ---- stage input halo tile (mostly-coalesced rows of 34) ----
        const int total = ICB * (TH + 2) * (TW + 2);       // 10880
        for (int i = tid; i < total; i += 256) {
            int ic = i / ((TH + 2) * (TW + 2));
            int r  = (i % ((TH + 2) * (TW + 2))) / (TW + 2);
            int c  = i % (TW + 2);
            int gh = h0 + r - 1;
            int gw = w0 + c - 1;
            float v = 0.f;
            if ((unsigned)gh < HW_ && (unsigned)gw < HW_)
                v = x[(((size_t)n * IC_ + icc + ic) * HW_ + gh) * HW_ + gw];
            sx[ic][r][c] = v;
        }
        __syncthreads();

        // ---- compute: 576 FMAs per ic-iteration, 9 LDS reads ----
        for (int ic = 0; ic < ICB; ++ic) {
            float xv[3][3];
            #pragma unroll
            for (int kh = 0; kh < 3; ++kh)
                #pragma unroll
                for (int kw = 0; kw < 3; ++kw)
                    xv[kh][kw] = sx[ic][ty + kh][tx + kw];

            #pragma unroll
            for (int kh = 0; kh < 3; ++kh)
            #pragma unroll
            for (int kw = 0; kw < 3; ++kw) {
                const float xvv = xv[kh][kw];
                #pragma unroll
                for (int oc = 0; oc < OC_; ++oc) {
                    float wv = REPACKED
                        ? Wt[(((icc + ic) * 3 + kh) * 3 + kw) * OC_ + oc]
                        : Wt[((oc * IC_ + icc + ic) * 3 + kh) * 3 + kw];
                    acc[oc] = fmaf(xvv, wv, acc[oc]);
                }
            }
        }
        __syncthreads();
    }

    #pragma unroll
    for (int oc = 0; oc < OC_; ++oc)
        out[(((size_t)n * OC_ + oc) * HW_ + h) * HW_ + w] = acc[oc];
}

extern "C" void kernel_launch(void* const* d_in, const int* in_sizes, int n_in,
                              void* d_out, int out_size, void* d_ws, size_t ws_size,
                              hipStream_t stream) {
    const float* x = (const float*)d_in[0];
    const float* W = (const float*)d_in[1];
    const float* b = (const float*)d_in[2];
    float* out = (float*)d_out;

    const size_t wt_bytes = (size_t)IC_ * 3 * 3 * OC_ * sizeof(float);  // 147456
    dim3 grid(HW_ / TW, HW_ / TH, N_);   // 8 x 32 x 16 = 4096 blocks
    dim3 block(TW, TH);                  // 256 threads

    if (ws_size >= wt_bytes) {
        float* Wt = (float*)d_ws;
        repack_w<<<(IC_ * 3 * 3 * OC_ + 255) / 256, 256, 0, stream>>>(W, Wt);
        conv3x3<true><<<grid, block, 0, stream>>>(x, Wt, b, out);
    } else {
        // Fallback: read W in original OIHW layout (still uniform -> s_load).
        conv3x3<false><<<grid, block, 0, stream>>>(x, W, b, out);
    }
}

// Round 2
// 654.261 us; speedup vs baseline: 3.4503x; 3.4503x over previous
//
#include <hip/hip_runtime.h>

// Conv2d(64->64, k=3, pad=1) + bias, fp32 NCHW 16x64x256x256.
// Round 2: bf16 MFMA implicit GEMM (threshold 0.12 permits bf16 inputs).
//   GEMM: D[oc][pix] = sum_{tap,ic} Wt[oc][tap,ic] * X[tap,ic][pix]
//   A = weights (m=oc, k), global 16B loads from d_ws repack [oc][tap][ic] bf16 (L1-hot).
//   B = pixels  (k, n=pix), from LDS tile [pixel][ic] (pitch 72 bf16 -> aligned b128,
//       banks hit the structural 8-clk floor).
//   C/D of 32x32x16: col=lane&31 -> pixel w (coalesced stores), row(reg) -> oc.

#define N_   16
#define C_   64
#define HW_  256
#define TH   8
#define TW   32
#define NPIX ((TH + 2) * (TW + 2))   // 340 staged pixels
#define ICP  72                      // LDS pitch in bf16 (144 B, keeps 16B chunks aligned)

typedef __attribute__((ext_vector_type(8)))  short short8;   // 8 bf16 = 4 VGPRs
typedef __attribute__((ext_vector_type(16))) float f32x16;   // 32x32 acc

static __device__ __forceinline__ unsigned short f2bf(float f) {
    unsigned u = __builtin_bit_cast(unsigned, f);
    return (unsigned short)((u + 0x7fffu + ((u >> 16) & 1u)) >> 16);   // RNE
}

// W OIHW fp32 -> Wt[oc][tap][ic] bf16
__global__ void repack_w_bf16(const float* __restrict__ W, unsigned short* __restrict__ Wt) {
    int i = blockIdx.x * 256 + threadIdx.x;          // 64*9*64 = 36864
    if (i < C_ * 9 * C_) {
        int ic = i & 63, tap = (i >> 6) % 9, oc = (i >> 6) / 9;
        Wt[i] = f2bf(W[(oc * C_ + ic) * 9 + tap]);
    }
}

__global__ __launch_bounds__(256, 3) void conv_mfma(const float* __restrict__ x,
                                                    const unsigned short* __restrict__ Wt,
                                                    const float* __restrict__ bias,
                                                    float* __restrict__ out) {
    __shared__ unsigned short sx[NPIX][ICP];         // 340*72*2 = 48960 B -> 3 blocks/CU

    const int tid  = threadIdx.x;
    const int L    = tid & 63, wv = tid >> 6;
    const int half = L >> 5,  lm = L & 31;
    const int w0 = blockIdx.x * TW, h0 = blockIdx.y * TH, n = blockIdx.z;

    // ---- acc init with bias (C-layout: oc = mf*32 + (r&3)+8*(r>>2)+4*half) ----
    f32x16 acc00, acc01, acc10, acc11;
    #pragma unroll
    for (int r = 0; r < 16; ++r) {
        int ro = (r & 3) + 8 * (r >> 2) + 4 * half;
        float b0 = bias[ro], b1 = bias[32 + ro];
        acc00[r] = b0; acc01[r] = b0;
        acc10[r] = b1; acc11[r] = b1;
    }

    // ---- stage x tile: fp32 NCHW -> bf16 LDS [pixel][ic] (2 ic per thread) ----
    const float* xn = x + (size_t)n * C_ * HW_ * HW_;
    for (int c = tid; c < NPIX * 32; c += 256) {
        int icp = c / NPIX;                  // ic pair index 0..31
        int p   = c - icp * NPIX;            // pixel 0..339 (lane-consecutive)
        int ph  = p / 34;
        int gh  = h0 + ph - 1, gw = w0 + (p - ph * 34) - 1;
        float v0 = 0.f, v1 = 0.f;
        if ((unsigned)gh < HW_ && (unsigned)gw < HW_) {
            const float* px = xn + ((size_t)(icp * 2) * HW_ + gh) * HW_ + gw;
            v0 = px[0];
            v1 = px[HW_ * HW_];
        }
        unsigned pk = (unsigned)f2bf(v0) | ((unsigned)f2bf(v1) << 16);
        *(unsigned*)&sx[p][icp * 2] = pk;
    }
    __syncthreads();

    // ---- K loop: 9 taps x 4 Ksteps of 16, 144 MFMAs ----
    const int r0 = 2 * wv;                                    // wave's output rows r0, r0+1
    const unsigned short* wr0 = Wt + (0 * 32 + lm) * 576;     // A m-dim: oc = mf*32 + lm
    const unsigned short* wr1 = Wt + (1 * 32 + lm) * 576;

    #pragma unroll
    for (int kh = 0; kh < 3; ++kh) {
        #pragma unroll
        for (int kw = 0; kw < 3; ++kw) {
            const int tap = kh * 3 + kw;
            const unsigned short* a0p = wr0 + tap * 64;
            const unsigned short* a1p = wr1 + tap * 64;
            const unsigned short* b0p = &sx[(r0 + kh) * 34 + lm + kw][0];
            const unsigned short* b1p = &sx[(r0 + 1 + kh) * 34 + lm + kw][0];
            #pragma unroll
            for (int s = 0; s < 4; ++s) {
                const int eo = s * 16 + half * 8;   // k = s*16 + half*8 + j
                short8 a0 = __builtin_bit_cast(short8, *(const uint4*)(a0p + eo));
                short8 a1 = __builtin_bit_cast(short8, *(const uint4*)(a1p + eo));
                short8 b0 = __builtin_bit_cast(short8, *(const uint4*)(b0p + eo));
                short8 b1 = __builtin_bit_cast(short8, *(const uint4*)(b1p + eo));
                acc00 = __builtin_amdgcn_mfma_f32_32x32x16_bf16(a0, b0, acc00, 0, 0, 0);
                acc01 = __builtin_amdgcn_mfma_f32_32x32x16_bf16(a0, b1, acc01, 0, 0, 0);
                acc10 = __builtin_amdgcn_mfma_f32_32x32x16_bf16(a1, b0, acc10, 0, 0, 0);
                acc11 = __builtin_amdgcn_mfma_f32_32x32x16_bf16(a1, b1, acc11, 0, 0, 0);
            }
        }
    }

    // ---- store: lane dim = w (128B segments), reg -> oc ----
    float* outn = out + (size_t)n * C_ * HW_ * HW_;
    #pragma unroll
    for (int r = 0; r < 16; ++r) {
        int ro = (r & 3) + 8 * (r >> 2) + 4 * half;
        size_t base0 = ((size_t)ro        * HW_ + (h0 + r0)) * HW_ + w0 + lm;
        size_t base1 = ((size_t)(32 + ro) * HW_ + (h0 + r0)) * HW_ + w0 + lm;
        outn[base0]       = acc00[r];
        outn[base0 + HW_] = acc01[r];   // next output row
        outn[base1]       = acc10[r];
        outn[base1 + HW_] = acc11[r];
    }
}

// ---- fp32 fallback (round-1 kernel) in case ws is too small for Wt ----
__global__ __launch_bounds__(256) void conv3x3_f32(const float* __restrict__ x,
                                                   const float* __restrict__ W,
                                                   const float* __restrict__ bias,
                                                   float* __restrict__ out) {
    __shared__ float fsx[32][TH + 2][TW + 2];
    const int tx = threadIdx.x & 31, ty = threadIdx.x >> 5;
    const int tid = threadIdx.x;
    const int w0 = blockIdx.x * TW, h0 = blockIdx.y * TH, n = blockIdx.z;
    float acc[C_];
    #pragma unroll
    for (int oc = 0; oc < C_; ++oc) acc[oc] = bias[oc];
    for (int icc = 0; icc < C_; icc += 32) {
        for (int i = tid; i < 32 * (TH + 2) * (TW + 2); i += 256) {
            int ic = i / ((TH + 2) * (TW + 2));
            int r  = (i % ((TH + 2) * (TW + 2))) / (TW + 2);
            int cc = i % (TW + 2);
            int gh = h0 + r - 1, gw = w0 + cc - 1;
            float v = 0.f;
            if ((unsigned)gh < HW_ && (unsigned)gw < HW_)
                v = x[(((size_t)n * C_ + icc + ic) * HW_ + gh) * HW_ + gw];
            fsx[ic][r][cc] = v;
        }
        __syncthreads();
        for (int ic = 0; ic < 32; ++ic) {
            #pragma unroll
            for (int kh = 0; kh < 3; ++kh)
            #pragma unroll
            for (int kw = 0; kw < 3; ++kw) {
                float xv = fsx[ic][ty + kh][tx + kw];
                #pragma unroll
                for (int oc = 0; oc < C_; ++oc)
                    acc[oc] = fmaf(xv, W[((oc * C_ + icc + ic) * 3 + kh) * 3 + kw], acc[oc]);
            }
        }
        __syncthreads();
    }
    #pragma unroll
    for (int oc = 0; oc < C_; ++oc)
        out[(((size_t)n * C_ + oc) * HW_ + h0 + ty) * HW_ + w0 + tx] = acc[oc];
}

extern "C" void kernel_launch(void* const* d_in, const int* in_sizes, int n_in,
                              void* d_out, int out_size, void* d_ws, size_t ws_size,
                              hipStream_t stream) {
    const float* x = (const float*)d_in[0];
    const float* W = (const float*)d_in[1];
    const float* b = (const float*)d_in[2];
    float* out = (float*)d_out;

    dim3 grid(HW_ / TW, HW_ / TH, N_);    // 8 x 32 x 16
    dim3 block(256);

    const size_t wt_bytes = (size_t)C_ * 9 * C_ * sizeof(unsigned short);  // 73728
    if (ws_size >= wt_bytes) {
        unsigned short* Wt = (unsigned short*)d_ws;
        repack_w_bf16<<<(C_ * 9 * C_ + 255) / 256, 256, 0, stream>>>(W, Wt);
        conv_mfma<<<grid, block, 0, stream>>>(x, Wt, b, out);
    } else {
        conv3x3_f32<<<grid, block, 0, stream>>>(x, W, b, out);
    }
}

// Round 3
// 643.795 us; speedup vs baseline: 3.5064x; 1.0163x over previous
//
#include <hip/hip_runtime.h>

// Conv2d(64->64, k=3, pad=1) + bias, fp32 NCHW 16x64x256x256.
// Round 3: two-pass. Pass 1 transposes x to bf16 NHWC in d_ws (BW-bound copy).
// Pass 2 = round-2 MFMA implicit GEMM, but staging is now a contiguous
// NHWC->LDS copy (dwordx4, 11 unrolled iters/thread) instead of scalar
// transpose-on-the-fly (which was latency-bound at 361us).

#define N_   16
#define C_   64
#define HW_  256
#define TH   8
#define TW   32
#define NPIX ((TH + 2) * (TW + 2))   // 340 staged pixels
#define ICP  72                      // LDS pitch in bf16 (144 B, 16B-aligned chunks)

typedef __attribute__((ext_vector_type(8)))  short short8;   // 8 bf16 = 4 VGPRs
typedef __attribute__((ext_vector_type(16))) float f32x16;   // 32x32 acc

static __device__ __forceinline__ unsigned short f2bf(float f) {
    unsigned u = __builtin_bit_cast(unsigned, f);
    return (unsigned short)((u + 0x7fffu + ((u >> 16) & 1u)) >> 16);   // RNE
}

// ---- pass 0: W OIHW fp32 -> Wt[oc][tap][ic] bf16 ----
__global__ void repack_w_bf16(const float* __restrict__ W, unsigned short* __restrict__ Wt) {
    int i = blockIdx.x * 256 + threadIdx.x;          // 64*9*64 = 36864
    if (i < C_ * 9 * C_) {
        int ic = i & 63, tap = (i >> 6) % 9, oc = (i >> 6) / 9;
        Wt[i] = f2bf(W[(oc * C_ + ic) * 9 + tap]);
    }
}

// ---- pass 1: x fp32 NCHW -> xt bf16 NHWC ----
__global__ __launch_bounds__(256) void transpose_nhwc(const float* __restrict__ x,
                                                      unsigned short* __restrict__ xt) {
    __shared__ unsigned short st[64][ICP];           // 64w x 64ic tile (pitch 72)
    const int tid = threadIdx.x;
    const int w0  = blockIdx.x * 64;                 // 0..3
    const int h   = blockIdx.y;
    const int n   = blockIdx.z;

    #pragma unroll
    for (int k = 0; k < 4; ++k) {
        int i  = tid + k * 256;                      // 0..1023
        int ic = i >> 4, seg = i & 15;               // 16 float4 per ic-row
        float4 v = *(const float4*)(x + (((size_t)(n * C_ + ic) * HW_ + h) * HW_ + w0 + seg * 4));
        st[seg * 4 + 0][ic] = f2bf(v.x);
        st[seg * 4 + 1][ic] = f2bf(v.y);
        st[seg * 4 + 2][ic] = f2bf(v.z);
        st[seg * 4 + 3][ic] = f2bf(v.w);
    }
    __syncthreads();
    #pragma unroll
    for (int j = 0; j < 2; ++j) {
        int w = (tid >> 3) + 32 * j, eg = tid & 7;
        uint4 v = *(const uint4*)&st[w][eg * 8];     // 16B-aligned (pitch 144B)
        *(uint4*)(xt + (((size_t)n * HW_ + h) * HW_ + w0 + w) * C_ + eg * 8) = v;
    }
}

// ---- pass 2: MFMA implicit GEMM from NHWC bf16 ----
__global__ __launch_bounds__(256, 3) void conv_mfma_nhwc(const unsigned short* __restrict__ xt,
                                                         const unsigned short* __restrict__ Wt,
                                                         const float* __restrict__ bias,
                                                         float* __restrict__ out) {
    __shared__ unsigned short sx[NPIX][ICP];         // 340*72*2 = 48960 B -> 3 blocks/CU

    const int tid  = threadIdx.x;
    const int L    = tid & 63, wv = tid >> 6;
    const int half = L >> 5,  lm = L & 31;
    const int w0 = blockIdx.x * TW, h0 = blockIdx.y * TH, n = blockIdx.z;

    // ---- stage halo tile: contiguous NHWC rows -> LDS [pixel][ic] ----
    const unsigned short* xtn = xt + (size_t)n * HW_ * HW_ * C_;
    #pragma unroll
    for (int k = 0; k < 11; ++k) {
        int i = tid + k * 256;                       // 16B chunks: 340 px * 8
        if (i < NPIX * 8) {
            int p = i >> 3, e = i & 7;
            int r = p / 34, col = p - r * 34;
            int gh = h0 + r - 1, gw = w0 + col - 1;
            uint4 v = make_uint4(0, 0, 0, 0);
            if ((unsigned)gh < HW_ && (unsigned)gw < HW_)
                v = *(const uint4*)(xtn + ((size_t)gh * HW_ + gw) * C_ + e * 8);
            *(uint4*)&sx[p][e * 8] = v;
        }
    }

    // ---- acc init with bias (C-layout: oc = mf*32 + (r&3)+8*(r>>2)+4*half) ----
    f32x16 acc00, acc01, acc10, acc11;
    #pragma unroll
    for (int r = 0; r < 16; ++r) {
        int ro = (r & 3) + 8 * (r >> 2) + 4 * half;
        float b0 = bias[ro], b1 = bias[32 + ro];
        acc00[r] = b0; acc01[r] = b0;
        acc10[r] = b1; acc11[r] = b1;
    }
    __syncthreads();

    // ---- K loop: 9 taps x 4 Ksteps of 16, 144 MFMAs ----
    const int r0 = 2 * wv;                                    // wave's output rows r0, r0+1
    const unsigned short* wr0 = Wt + (0 * 32 + lm) * 576;     // A m-dim: oc = mf*32 + lm
    const unsigned short* wr1 = Wt + (1 * 32 + lm) * 576;

    #pragma unroll
    for (int kh = 0; kh < 3; ++kh) {
        #pragma unroll
        for (int kw = 0; kw < 3; ++kw) {
            const int tap = kh * 3 + kw;
            const unsigned short* a0p = wr0 + tap * 64;
            const unsigned short* a1p = wr1 + tap * 64;
            const unsigned short* b0p = &sx[(r0 + kh) * 34 + lm + kw][0];
            const unsigned short* b1p = &sx[(r0 + 1 + kh) * 34 + lm + kw][0];
            #pragma unroll
            for (int s = 0; s < 4; ++s) {
                const int eo = s * 16 + half * 8;   // k = s*16 + half*8 + j
                short8 a0 = __builtin_bit_cast(short8, *(const uint4*)(a0p + eo));
                short8 a1 = __builtin_bit_cast(short8, *(const uint4*)(a1p + eo));
                short8 b0 = __builtin_bit_cast(short8, *(const uint4*)(b0p + eo));
                short8 b1 = __builtin_bit_cast(short8, *(const uint4*)(b1p + eo));
                acc00 = __builtin_amdgcn_mfma_f32_32x32x16_bf16(a0, b0, acc00, 0, 0, 0);
                acc01 = __builtin_amdgcn_mfma_f32_32x32x16_bf16(a0, b1, acc01, 0, 0, 0);
                acc10 = __builtin_amdgcn_mfma_f32_32x32x16_bf16(a1, b0, acc10, 0, 0, 0);
                acc11 = __builtin_amdgcn_mfma_f32_32x32x16_bf16(a1, b1, acc11, 0, 0, 0);
            }
        }
    }

    // ---- store: lane dim = w (128B segments), reg -> oc ----
    float* outn = out + (size_t)n * C_ * HW_ * HW_;
    #pragma unroll
    for (int r = 0; r < 16; ++r) {
        int ro = (r & 3) + 8 * (r >> 2) + 4 * half;
        size_t base0 = ((size_t)ro        * HW_ + (h0 + r0)) * HW_ + w0 + lm;
        size_t base1 = ((size_t)(32 + ro) * HW_ + (h0 + r0)) * HW_ + w0 + lm;
        outn[base0]       = acc00[r];
        outn[base0 + HW_] = acc01[r];
        outn[base1]       = acc10[r];
        outn[base1 + HW_] = acc11[r];
    }
}

// ---- fallback: round-2 kernel (fp32 NCHW source, scalar transpose staging) ----
__global__ __launch_bounds__(256, 3) void conv_mfma_f32src(const float* __restrict__ x,
                                                           const unsigned short* __restrict__ Wt,
                                                           const float* __restrict__ bias,
                                                           float* __restrict__ out) {
    __shared__ unsigned short sx[NPIX][ICP];
    const int tid  = threadIdx.x;
    const int L    = tid & 63, wv = tid >> 6;
    const int half = L >> 5,  lm = L & 31;
    const int w0 = blockIdx.x * TW, h0 = blockIdx.y * TH, n = blockIdx.z;

    f32x16 acc00, acc01, acc10, acc11;
    #pragma unroll
    for (int r = 0; r < 16; ++r) {
        int ro = (r & 3) + 8 * (r >> 2) + 4 * half;
        float b0 = bias[ro], b1 = bias[32 + ro];
        acc00[r] = b0; acc01[r] = b0;
        acc10[r] = b1; acc11[r] = b1;
    }

    const float* xn = x + (size_t)n * C_ * HW_ * HW_;
    for (int c = tid; c < NPIX * 32; c += 256) {
        int icp = c / NPIX;
        int p   = c - icp * NPIX;
        int ph  = p / 34;
        int gh  = h0 + ph - 1, gw = w0 + (p - ph * 34) - 1;
        float v0 = 0.f, v1 = 0.f;
        if ((unsigned)gh < HW_ && (unsigned)gw < HW_) {
            const float* px = xn + ((size_t)(icp * 2) * HW_ + gh) * HW_ + gw;
            v0 = px[0];
            v1 = px[HW_ * HW_];
        }
        unsigned pk = (unsigned)f2bf(v0) | ((unsigned)f2bf(v1) << 16);
        *(unsigned*)&sx[p][icp * 2] = pk;
    }
    __syncthreads();

    const int r0 = 2 * wv;
    const unsigned short* wr0 = Wt + (0 * 32 + lm) * 576;
    const unsigned short* wr1 = Wt + (1 * 32 + lm) * 576;
    #pragma unroll
    for (int kh = 0; kh < 3; ++kh) {
        #pragma unroll
        for (int kw = 0; kw < 3; ++kw) {
            const int tap = kh * 3 + kw;
            const unsigned short* a0p = wr0 + tap * 64;
            const unsigned short* a1p = wr1 + tap * 64;
            const unsigned short* b0p = &sx[(r0 + kh) * 34 + lm + kw][0];
            const unsigned short* b1p = &sx[(r0 + 1 + kh) * 34 + lm + kw][0];
            #pragma unroll
            for (int s = 0; s < 4; ++s) {
                const int eo = s * 16 + half * 8;
                short8 a0 = __builtin_bit_cast(short8, *(const uint4*)(a0p + eo));
                short8 a1 = __builtin_bit_cast(short8, *(const uint4*)(a1p + eo));
                short8 b0 = __builtin_bit_cast(short8, *(const uint4*)(b0p + eo));
                short8 b1 = __builtin_bit_cast(short8, *(const uint4*)(b1p + eo));
                acc00 = __builtin_amdgcn_mfma_f32_32x32x16_bf16(a0, b0, acc00, 0, 0, 0);
                acc01 = __builtin_amdgcn_mfma_f32_32x32x16_bf16(a0, b1, acc01, 0, 0, 0);
                acc10 = __builtin_amdgcn_mfma_f32_32x32x16_bf16(a1, b0, acc10, 0, 0, 0);
                acc11 = __builtin_amdgcn_mfma_f32_32x32x16_bf16(a1, b1, acc11, 0, 0, 0);
            }
        }
    }

    float* outn = out + (size_t)n * C_ * HW_ * HW_;
    #pragma unroll
    for (int r = 0; r < 16; ++r) {
        int ro = (r & 3) + 8 * (r >> 2) + 4 * half;
        size_t base0 = ((size_t)ro        * HW_ + (h0 + r0)) * HW_ + w0 + lm;
        size_t base1 = ((size_t)(32 + ro) * HW_ + (h0 + r0)) * HW_ + w0 + lm;
        outn[base0]       = acc00[r];
        outn[base0 + HW_] = acc01[r];
        outn[base1]       = acc10[r];
        outn[base1 + HW_] = acc11[r];
    }
}

extern "C" void kernel_launch(void* const* d_in, const int* in_sizes, int n_in,
                              void* d_out, int out_size, void* d_ws, size_t ws_size,
                              hipStream_t stream) {
    const float* x = (const float*)d_in[0];
    const float* W = (const float*)d_in[1];
    const float* b = (const float*)d_in[2];
    float* out = (float*)d_out;

    dim3 grid(HW_ / TW, HW_ / TH, N_);    // 8 x 32 x 16
    dim3 block(256);

    const size_t xt_bytes = (size_t)N_ * HW_ * HW_ * C_ * sizeof(unsigned short);  // 128 MiB
    const size_t wt_bytes = (size_t)C_ * 9 * C_ * sizeof(unsigned short);          // 72 KiB

    if (ws_size >= xt_bytes + wt_bytes) {
        unsigned short* xt = (unsigned short*)d_ws;
        unsigned short* Wt = (unsigned short*)d_ws + xt_bytes / 2;
        repack_w_bf16<<<(C_ * 9 * C_ + 255) / 256, 256, 0, stream>>>(W, Wt);
        transpose_nhwc<<<dim3(4, HW_, N_), 256, 0, stream>>>(x, xt);
        conv_mfma_nhwc<<<grid, block, 0, stream>>>(xt, Wt, b, out);
    } else if (ws_size >= wt_bytes) {
        unsigned short* Wt = (unsigned short*)d_ws;
        repack_w_bf16<<<(C_ * 9 * C_ + 255) / 256, 256, 0, stream>>>(W, Wt);
        conv_mfma_f32src<<<grid, block, 0, stream>>>(x, Wt, b, out);
    }
}